// Round 1
// baseline (1488.753 us; speedup 1.0000x reference)
//
#include <hip/hip_runtime.h>

// Wav2Vec2 Gumbel VQ — round 1: fused fp32 GEMM + epilogue (correctness-first).
// B=32 S=2048 D=512 G=2 K=320 -> N=65536 rows, GK=640 cols, out (N,256) + perplexity.

#define DD   512
#define GG   2
#define KK   320
#define NN   65536
#define DPG  128
#define EPSL 1e-7f

#define BM   32      // rows per block
#define BK   16      // k-chunk
#define NT   320     // threads per block (5 waves)
#define HS   36      // H_lds stride (pad, mult of 4 for b128 align)
#define WS   324     // W_lds stride (pad, mult of 4)
#define PS   321     // logits tile stride (breaks 32-bank aliasing)

__global__ __launch_bounds__(NT) void fused_vq_kernel(
    const float* __restrict__ H, const int* __restrict__ mask,
    const float* __restrict__ gumbel, const float* __restrict__ W,
    const float* __restrict__ bias, const float* __restrict__ cv,
    float* __restrict__ out, float* __restrict__ marg)
{
    __shared__ __align__(16) float smem[BM * PS];   // 10272 f: staging aliases front, then P tile
    __shared__ float pmax[NT], psum[NT], pav[NT];
    __shared__ int   pai[NT];
    __shared__ float rowmax[BM], wrow[BM], maskf[BM];
    __shared__ int   rowidx[BM];

    float* Hl = smem;              // [BK][HS] transposed: Hl[k*HS + row]
    float* Wl = smem + BK * HS;    // [BK][WS] transposed: Wl[k*WS + col]

    const int tid = threadIdx.x;
    const int bx  = blockIdx.x;
    const int g   = bx & 1;
    const int n0  = (bx >> 1) * BM;

    const int tc = tid % 40;       // 40 thread-cols * 8 cols
    const int tr = tid / 40;       // 8 thread-rows * 4 rows

    const float* Hg = H + (size_t)n0 * DD;
    const float* Wg = W + (size_t)g * KK * DD;

    float acc[4][8];
#pragma unroll
    for (int rr = 0; rr < 4; ++rr)
#pragma unroll
        for (int cc = 0; cc < 8; ++cc) acc[rr][cc] = 0.0f;

    for (int kc = 0; kc < DD; kc += BK) {
        // stage H tile 32 rows x 16 k, transposed into Hl[k][row]
        for (int e = tid; e < BM * BK; e += NT) {
            int row = e >> 4, k = e & 15;
            Hl[k * HS + row] = Hg[(size_t)row * DD + kc + k];
        }
        // stage W tile 320 cols x 16 k, transposed into Wl[k][col]
        for (int e = tid; e < KK * BK; e += NT) {
            int col = e >> 4, k = e & 15;
            Wl[k * WS + col] = Wg[(size_t)col * DD + kc + k];
        }
        __syncthreads();
#pragma unroll
        for (int k = 0; k < BK; ++k) {
            const float4 a  = *(const float4*)(Hl + k * HS + 4 * tr);
            const float4 b0 = *(const float4*)(Wl + k * WS + 8 * tc);
            const float4 b1 = *(const float4*)(Wl + k * WS + 8 * tc + 4);
            float ar[4] = {a.x, a.y, a.z, a.w};
            float br[8] = {b0.x, b0.y, b0.z, b0.w, b1.x, b1.y, b1.z, b1.w};
#pragma unroll
            for (int rr = 0; rr < 4; ++rr)
#pragma unroll
                for (int cc = 0; cc < 8; ++cc)
                    acc[rr][cc] = fmaf(ar[rr], br[cc], acc[rr][cc]);
        }
        __syncthreads();
    }

    // ---- epilogue: logits (+bias) into smem as P[BM][PS] ----
    float bcol[8];
#pragma unroll
    for (int cc = 0; cc < 8; ++cc) bcol[cc] = bias[g * KK + 8 * tc + cc];
#pragma unroll
    for (int rr = 0; rr < 4; ++rr) {
        int row = 4 * tr + rr;
#pragma unroll
        for (int cc = 0; cc < 8; ++cc)
            smem[row * PS + 8 * tc + cc] = acc[rr][cc] + bcol[cc];
    }
    if (tid < BM) maskf[tid] = (mask[n0 + tid] != 0) ? 1.0f : 0.0f;
    __syncthreads();

    // per-(row,slot): slot covers cols [32*slot, 32*slot+32)
    const int erow = tid / 10;
    const int slot = tid % 10;
    {
        const float* gp = gumbel + ((size_t)(n0 + erow) * GG + g) * KK;
        float mloc = -3.0e38f, av = -3.0e38f;
        int   ai = 32 * slot;
        for (int c0 = 0; c0 < 32; ++c0) {
            int c = 32 * slot + c0;
            float l = smem[erow * PS + c];
            mloc = fmaxf(mloc, l);
            float z = l + gp[c];
            if (z > av) { av = z; ai = c; }   // strict >: first max wins (jnp.argmax tie rule)
        }
        pmax[tid] = mloc; pav[tid] = av; pai[tid] = ai;
    }
    __syncthreads();
    if (slot == 0) {
        float m = pmax[tid], av = pav[tid];
        int ai = pai[tid];
        for (int j = 1; j < 10; ++j) {        // ascending slot: preserves first-index ties
            m = fmaxf(m, pmax[tid + j]);
            if (pav[tid + j] > av) { av = pav[tid + j]; ai = pai[tid + j]; }
        }
        rowmax[erow] = m; rowidx[erow] = ai;
    }
    __syncthreads();
    {
        float rm = rowmax[erow];
        float s = 0.0f;
        for (int c0 = 0; c0 < 32; ++c0) {
            int c = 32 * slot + c0;
            float e = expf(smem[erow * PS + c] - rm);
            smem[erow * PS + c] = e;          // overwrite logits with unnormalized p
            s += e;
        }
        psum[tid] = s;
    }
    __syncthreads();
    if (slot == 0) {
        float s = 0.0f;
        for (int j = 0; j < 10; ++j) s += psum[tid + j];
        wrow[erow] = maskf[erow] / s;         // mask-weighted 1/Z per row
    }
    __syncthreads();

    // block-local marginal per col, one atomic per col
    {
        float s = 0.0f;
        for (int r = 0; r < BM; ++r) s += smem[r * PS + tid] * wrow[r];
        atomicAdd(&marg[g * KK + tid], s);
    }

    // codevector gather: out[n, g*128 + d] = cv[g, idx[n], d]
    for (int e = tid; e < BM * DPG; e += NT) {
        int row = e >> 7, d = e & 127;
        out[(size_t)(n0 + row) * (GG * DPG) + g * DPG + d] =
            cv[((size_t)g * KK + rowidx[row]) * DPG + d];
    }
}

__global__ __launch_bounds__(256) void finalize_kernel(
    const int* __restrict__ mask, const float* __restrict__ marg,
    float* __restrict__ perp_out)
{
    __shared__ float red[256];
    __shared__ float hg[GG];
    const int tid = threadIdx.x;

    int cnt = 0;
    for (int n = tid; n < NN; n += 256) cnt += (mask[n] != 0) ? 1 : 0;
    red[tid] = (float)cnt;
    __syncthreads();
    for (int s = 128; s > 0; s >>= 1) {
        if (tid < s) red[tid] += red[tid + s];
        __syncthreads();
    }
    const float invc = 1.0f / red[0];
    __syncthreads();

    for (int g = 0; g < GG; ++g) {
        float h = 0.0f;
        for (int c = tid; c < KK; c += 256) {
            float m = marg[g * KK + c] * invc;
            h += m * logf(m + EPSL);
        }
        red[tid] = h;
        __syncthreads();
        for (int s = 128; s > 0; s >>= 1) {
            if (tid < s) red[tid] += red[tid + s];
            __syncthreads();
        }
        if (tid == 0) hg[g] = red[0];
        __syncthreads();
    }
    if (tid == 0) perp_out[0] = expf(-hg[0]) + expf(-hg[1]);
}

extern "C" void kernel_launch(void* const* d_in, const int* in_sizes, int n_in,
                              void* d_out, int out_size, void* d_ws, size_t ws_size,
                              hipStream_t stream)
{
    const float* H      = (const float*)d_in[0];   // (32,2048,512) f32
    const int*   mask   = (const int*)d_in[1];     // (32,2048) bool->int32
    const float* gumbel = (const float*)d_in[2];   // (131072,320) f32
    const float* W      = (const float*)d_in[3];   // (640,512) f32
    const float* bias   = (const float*)d_in[4];   // (640,) f32
    const float* cv     = (const float*)d_in[5];   // (1,640,128) f32

    float* out  = (float*)d_out;                   // 16777216 + 1 floats
    float* marg = (float*)d_ws;                    // 640 floats accumulator

    hipMemsetAsync(marg, 0, GG * KK * sizeof(float), stream);

    const int nblocks = (NN / BM) * GG;            // 4096
    fused_vq_kernel<<<nblocks, NT, 0, stream>>>(H, mask, gumbel, W, bias, cv, out, marg);
    finalize_kernel<<<1, 256, 0, stream>>>(mask, marg, out + (size_t)NN * GG * DPG);
}

// Round 2
// 264.508 us; speedup vs baseline: 5.6284x; 5.6284x over previous
//
#include <hip/hip_runtime.h>

// Wav2Vec2 Gumbel VQ — round 2: f16 hi/lo 3-split MFMA GEMM + fused epilogue.
// logits = H(65536x512) @ W^T(512x640); argmax(logits+gumbel) -> codevector gather;
// softmax(logits) -> masked marginal -> perplexity.

#define GG   2
#define KK   320
#define NN   65536
#define DD   512
#define DPG  128
#define EPSL 1e-7f

typedef __attribute__((ext_vector_type(8))) _Float16 f16x8;
typedef __attribute__((ext_vector_type(4))) _Float16 f16x4;
typedef __attribute__((ext_vector_type(4))) float    f32x4;

// ---------- prep: W (640x512 f32) -> fragment-ordered f16 hi/lo ----------
// Wf element offset for (ct,t,p,l,j) = ((ct*16+t)*2+p)*512 + l*8 + j
// frag: col = 16*ct + (l&15), k = 32*t + 8*(l>>4) + j   (B-frag layout)
__global__ __launch_bounds__(256) void prep_w(const float* __restrict__ W,
                                              _Float16* __restrict__ Wf) {
    int gt = blockIdx.x * 256 + threadIdx.x;          // 40960 threads total
    int w  = gt >> 6, l = gt & 63;                    // w = ct*16 + t (640 waves)
    int col = 16 * (w >> 4) + (l & 15);
    int k0  = 32 * (w & 15) + 8 * (l >> 4);
    const float* src = W + (size_t)col * DD + k0;
    float4 v0 = *(const float4*)(src);
    float4 v1 = *(const float4*)(src + 4);
    float vv[8] = {v0.x, v0.y, v0.z, v0.w, v1.x, v1.y, v1.z, v1.w};
    f16x8 hi, lo;
#pragma unroll
    for (int j = 0; j < 8; ++j) {
        _Float16 h = (_Float16)vv[j];
        hi[j] = h;
        lo[j] = (_Float16)(vv[j] - (float)h);
    }
    size_t base = (size_t)w * 1024 + (size_t)l * 8;
    *(f16x8*)(Wf + base)       = hi;
    *(f16x8*)(Wf + base + 512) = lo;
}

// ---------- main fused kernel ----------
// grid: 1024 blocks = 512 row-blocks (128 rows) x 2 groups. 256 thr = 4 waves.
// wave (wr,wc): rows R0+0..63 (4 frag-rows), cols C0+0..159 (10 frag-cols) of group g.
__global__ __launch_bounds__(256, 2) void vq_main(
    const float* __restrict__ H, const int* __restrict__ mask,
    const float* __restrict__ gumbel, const _Float16* __restrict__ Wf,
    const float* __restrict__ bias, const float* __restrict__ cv,
    float* __restrict__ out, float* __restrict__ marg)
{
    // A staging: [buf][frag-row(8)][plane(2)][lane(64)][j(8)] f16 = 32 KB
    __shared__ _Float16 Albuf[2][8][2][64][8];
    __shared__ float red_m[128][2], red_s[128][2], red_z[128][2];
    __shared__ int   red_i[128][2];
    __shared__ float mfin[128], wrow[128];
    __shared__ int   idxf[128];

    const int tid = threadIdx.x;
    const int l   = tid & 63, wid = tid >> 6;
    const int wr  = wid >> 1, wc = wid & 1;
    const int g   = blockIdx.x & 1;
    const int n0  = (blockIdx.x >> 1) * 128;
    const int q   = l >> 4, ln = l & 15;
    const int R0  = 64 * wr, C0 = 160 * wc;

    // staging assignment: thread stages row srow = tid>>1, k-half mh = tid&1
    const int srow = tid >> 1, mh = tid & 1;
    const float* Hp = H + (size_t)(n0 + srow) * DD + 16 * mh;
    const int srf = srow >> 4, slb = srow & 15;

    f32x4 acc[4][10];
    const f32x4 vzero = {0.f, 0.f, 0.f, 0.f};
#pragma unroll
    for (int a = 0; a < 4; ++a)
#pragma unroll
        for (int b = 0; b < 10; ++b) acc[a][b] = vzero;

    float4 st[4];
#pragma unroll
    for (int i = 0; i < 4; ++i) st[i] = *(const float4*)(Hp + 4 * i);

    const _Float16* Wbase = Wf + (size_t)(g * 20 + wc * 10) * 16384 + (size_t)l * 8;

    // convert staged fp32 regs -> hi/lo f16, write to LDS buffer `buf`
#define WRITE_STAGE(buf)                                                        \
    {                                                                           \
        _Pragma("unroll")                                                       \
        for (int i = 0; i < 4; ++i) {                                           \
            int kl   = 16 * mh + 4 * i;                                         \
            int lidx = slb | ((kl >> 3) << 4);                                  \
            int j0   = kl & 7;                                                  \
            float vv[4] = {st[i].x, st[i].y, st[i].z, st[i].w};                 \
            f16x4 h, lo;                                                        \
            _Pragma("unroll")                                                   \
            for (int j = 0; j < 4; ++j) {                                       \
                _Float16 hh = (_Float16)vv[j];                                  \
                h[j]  = hh;                                                     \
                lo[j] = (_Float16)(vv[j] - (float)hh);                          \
            }                                                                   \
            *(f16x4*)&Albuf[buf][srf][0][lidx][j0] = h;                         \
            *(f16x4*)&Albuf[buf][srf][1][lidx][j0] = lo;                        \
        }                                                                       \
    }

    WRITE_STAGE(0)
    __syncthreads();

    for (int t = 0; t < 16; ++t) {
        const int cur = t & 1;
        if (t < 15) {
#pragma unroll
            for (int i = 0; i < 4; ++i)
                st[i] = *(const float4*)(Hp + (t + 1) * 32 + 4 * i);
        }
        f16x8 Ah[4], Al[4];
#pragma unroll
        for (int rf = 0; rf < 4; ++rf) {
            Ah[rf] = *(const f16x8*)&Albuf[cur][wr * 4 + rf][0][l][0];
            Al[rf] = *(const f16x8*)&Albuf[cur][wr * 4 + rf][1][l][0];
        }
#pragma unroll
        for (int cf = 0; cf < 10; ++cf) {
            const _Float16* wp = Wbase + (size_t)cf * 16384 + (size_t)t * 1024;
            f16x8 Bh = *(const f16x8*)wp;
            f16x8 Bl = *(const f16x8*)(wp + 512);
#pragma unroll
            for (int rf = 0; rf < 4; ++rf)
                acc[rf][cf] = __builtin_amdgcn_mfma_f32_16x16x32_f16(Ah[rf], Bh, acc[rf][cf], 0, 0, 0);
#pragma unroll
            for (int rf = 0; rf < 4; ++rf)
                acc[rf][cf] = __builtin_amdgcn_mfma_f32_16x16x32_f16(Ah[rf], Bl, acc[rf][cf], 0, 0, 0);
#pragma unroll
            for (int rf = 0; rf < 4; ++rf)
                acc[rf][cf] = __builtin_amdgcn_mfma_f32_16x16x32_f16(Al[rf], Bh, acc[rf][cf], 0, 0, 0);
        }
        if (t < 15) WRITE_STAGE(cur ^ 1)
        __syncthreads();
    }

    // ---- epilogue: bias ----
#pragma unroll
    for (int cf = 0; cf < 10; ++cf) {
        float bb = bias[g * KK + C0 + 16 * cf + ln];
#pragma unroll
        for (int rf = 0; rf < 4; ++rf) {
            acc[rf][cf][0] += bb; acc[rf][cf][1] += bb;
            acc[rf][cf][2] += bb; acc[rf][cf][3] += bb;
        }
    }

    // ---- per-row stats: logit max, gumbel argmax, sum-exp (16-lane groups) ----
#pragma unroll
    for (int rf = 0; rf < 4; ++rf) {
#pragma unroll
        for (int reg = 0; reg < 4; ++reg) {
            const int row = R0 + 16 * rf + 4 * q + reg;
            const float* gp = gumbel + ((size_t)(n0 + row) * GG + g) * KK + C0 + ln;
            float lm = -3.0e38f, zm = -3.0e38f;
            int zi = 0;
#pragma unroll
            for (int cf = 0; cf < 10; ++cf) {
                float v = acc[rf][cf][reg];
                lm = fmaxf(lm, v);
                float z = v + gp[16 * cf];
                if (z > zm) { zm = z; zi = C0 + 16 * cf + ln; }  // strict >: first-index tie rule
            }
#pragma unroll
            for (int d = 1; d <= 8; d <<= 1) {
                lm = fmaxf(lm, __shfl_xor(lm, d));
                float zo = __shfl_xor(zm, d);
                int   io = __shfl_xor(zi, d);
                if (zo > zm || (zo == zm && io < zi)) { zm = zo; zi = io; }
            }
            float s = 0.f;
#pragma unroll
            for (int cf = 0; cf < 10; ++cf) s += __expf(acc[rf][cf][reg] - lm);
#pragma unroll
            for (int d = 1; d <= 8; d <<= 1) s += __shfl_xor(s, d);
            if (ln == 0) {
                red_m[row][wc] = lm; red_s[row][wc] = s;
                red_z[row][wc] = zm; red_i[row][wc] = zi;
            }
        }
    }
    __syncthreads();

    // ---- combine the two col-halves per row ----
    if (tid < 128) {
        float m0 = red_m[tid][0], m1 = red_m[tid][1];
        float m  = fmaxf(m0, m1);
        float Z  = red_s[tid][0] * __expf(m0 - m) + red_s[tid][1] * __expf(m1 - m);
        float z0 = red_z[tid][0], z1 = red_z[tid][1];
        idxf[tid] = (z0 >= z1) ? red_i[tid][0] : red_i[tid][1];  // tie -> lower cols (half 0)
        mfin[tid] = m;
        wrow[tid] = ((mask[n0 + tid] != 0) ? 1.0f : 0.0f) / Z;
    }
    __syncthreads();

    // ---- marginal: col partial sums over this block's 128 rows ----
    float cs[10];
#pragma unroll
    for (int cf = 0; cf < 10; ++cf) cs[cf] = 0.f;
#pragma unroll
    for (int rf = 0; rf < 4; ++rf) {
#pragma unroll
        for (int reg = 0; reg < 4; ++reg) {
            const int row = R0 + 16 * rf + 4 * q + reg;
            const float mf = mfin[row], wv = wrow[row];
#pragma unroll
            for (int cf = 0; cf < 10; ++cf)
                cs[cf] += __expf(acc[rf][cf][reg] - mf) * wv;
        }
    }
#pragma unroll
    for (int cf = 0; cf < 10; ++cf) {
        float v = cs[cf];
        v += __shfl_xor(v, 16);
        v += __shfl_xor(v, 32);
        if (l < 16) atomicAdd(&marg[g * KK + C0 + 16 * cf + l], v);
    }

    // ---- codevector gather ----
    for (int e = tid; e < 128 * DPG; e += 256) {
        int row = e >> 7, d = e & 127;
        out[(size_t)(n0 + row) * (GG * DPG) + g * DPG + d] =
            cv[((size_t)g * KK + idxf[row]) * DPG + d];
    }
}

// ---------- perplexity finalize ----------
__global__ __launch_bounds__(256) void finalize_kernel(
    const int* __restrict__ mask, const float* __restrict__ marg,
    float* __restrict__ perp_out)
{
    __shared__ float red[256];
    __shared__ float hg[GG];
    const int tid = threadIdx.x;

    int cnt = 0;
    for (int n = tid; n < NN; n += 256) cnt += (mask[n] != 0) ? 1 : 0;
    red[tid] = (float)cnt;
    __syncthreads();
    for (int s = 128; s > 0; s >>= 1) {
        if (tid < s) red[tid] += red[tid + s];
        __syncthreads();
    }
    const float invc = 1.0f / red[0];
    __syncthreads();

    for (int g = 0; g < GG; ++g) {
        float h = 0.0f;
        for (int c = tid; c < KK; c += 256) {
            float m = marg[g * KK + c] * invc;
            h += m * logf(m + EPSL);
        }
        red[tid] = h;
        __syncthreads();
        for (int s = 128; s > 0; s >>= 1) {
            if (tid < s) red[tid] += red[tid + s];
            __syncthreads();
        }
        if (tid == 0) hg[g] = red[0];
        __syncthreads();
    }
    if (tid == 0) perp_out[0] = expf(-hg[0]) + expf(-hg[1]);
}

extern "C" void kernel_launch(void* const* d_in, const int* in_sizes, int n_in,
                              void* d_out, int out_size, void* d_ws, size_t ws_size,
                              hipStream_t stream)
{
    const float* H      = (const float*)d_in[0];   // (32,2048,512) f32
    const int*   mask   = (const int*)d_in[1];     // (32,2048) bool->int32
    const float* gumbel = (const float*)d_in[2];   // (131072,320) f32
    const float* W      = (const float*)d_in[3];   // (640,512) f32
    const float* bias   = (const float*)d_in[4];   // (640,) f32
    const float* cv     = (const float*)d_in[5];   // (1,640,128) f32

    float*     out  = (float*)d_out;               // 16777216 + 1 floats
    float*     marg = (float*)d_ws;                // 640 f32 accumulator
    _Float16*  Wf   = (_Float16*)((char*)d_ws + 4096);  // 1.31 MB f16 frags

    hipMemsetAsync(marg, 0, GG * KK * sizeof(float), stream);
    prep_w<<<160, 256, 0, stream>>>(W, Wf);
    vq_main<<<1024, 256, 0, stream>>>(H, mask, gumbel, Wf, bias, cv, out, marg);
    finalize_kernel<<<1, 256, 0, stream>>>(mask, marg, out + (size_t)NN * GG * DPG);
}

// Round 3
// 258.301 us; speedup vs baseline: 5.7636x; 1.0240x over previous
//
#include <hip/hip_runtime.h>

// Wav2Vec2 Gumbel VQ — round 3: barrier-free MFMA K-loop.
// prep_w: W -> fragment-ordered f16 hi/lo in d_ws (L2-resident).
// vq_main: per block, convert 64-row H tile to fragment-ordered hi/lo f16 in LDS
//          (128 KiB, once), then a K-loop with NO barriers: ds_read A + L2 W loads
//          + 60 MFMA per t per wave. Epilogue reuses LDS.

#define GG   2
#define KK   320
#define NN   65536
#define DD   512
#define DPG  128
#define EPSL 1e-7f

typedef __attribute__((ext_vector_type(8))) _Float16 f16x8;
typedef __attribute__((ext_vector_type(4))) float    f32x4;

// ---------- prep: W (640x512 f32) -> fragment-ordered f16 hi/lo ----------
// Wf element offset for (ct,t,p,l,j) = ((ct*16+t)*2+p)*512 + l*8 + j
// frag: col = 16*ct + (l&15), k = 32*t + 8*(l>>4) + j   (B-frag layout, verified r2)
__global__ __launch_bounds__(256) void prep_w(const float* __restrict__ W,
                                              _Float16* __restrict__ Wf) {
    int gt = blockIdx.x * 256 + threadIdx.x;          // 40960 threads
    int w  = gt >> 6, l = gt & 63;                    // w = ct*16 + t
    int col = 16 * (w >> 4) + (l & 15);
    int k0  = 32 * (w & 15) + 8 * (l >> 4);
    const float* src = W + (size_t)col * DD + k0;
    float4 v0 = *(const float4*)(src);
    float4 v1 = *(const float4*)(src + 4);
    float vv[8] = {v0.x, v0.y, v0.z, v0.w, v1.x, v1.y, v1.z, v1.w};
    f16x8 hi, lo;
#pragma unroll
    for (int j = 0; j < 8; ++j) {
        _Float16 h = (_Float16)vv[j];
        hi[j] = h;
        lo[j] = (_Float16)(vv[j] - (float)h);
    }
    size_t base = (size_t)w * 1024 + (size_t)l * 8;
    *(f16x8*)(Wf + base)       = hi;
    *(f16x8*)(Wf + base + 512) = lo;
}

// ---------- main fused kernel ----------
// grid: 1024 blocks (64 rows each, ALL 640 cols). 512 thr = 8 waves.
// wave w: group g=w>>2, col-half hc=w&3 -> cols g*320 + hc*80 .. +79 (5 cf), rows 0..63 (4 rf).
__global__ __launch_bounds__(512, 2) void vq_main(
    const float* __restrict__ H, const int* __restrict__ mask,
    const float* __restrict__ gumbel, const _Float16* __restrict__ Wf,
    const float* __restrict__ bias, const float* __restrict__ cv,
    float* __restrict__ out, float* __restrict__ marg)
{
    // 128 KiB: K-loop A tile, then reused for epilogue reductions.
    __shared__ __align__(16) char smem[131072];
    _Float16* Alds = (_Float16*)smem;   // [frag(64) = rf*16+t][plane(2)][lane(64)][j(8)]

    const int tid = threadIdx.x;
    const int l   = tid & 63, w = tid >> 6;
    const int g   = w >> 2,  hc = w & 3;
    const int n0  = blockIdx.x * 64;
    const int q   = l >> 4,  ln = l & 15;

    // ---- stage & convert A tile: wave w handles frags 8w..8w+7 (conflict-free writes) ----
    for (int f = 8 * w; f < 8 * w + 8; ++f) {
        const int rf = f >> 4, t = f & 15;
        const float* src = H + (size_t)(n0 + 16 * rf + ln) * DD + 32 * t + 8 * q;
        float4 v0 = *(const float4*)src;
        float4 v1 = *(const float4*)(src + 4);
        float vv[8] = {v0.x, v0.y, v0.z, v0.w, v1.x, v1.y, v1.z, v1.w};
        f16x8 hi, lo;
#pragma unroll
        for (int j = 0; j < 8; ++j) {
            _Float16 h = (_Float16)vv[j];
            hi[j] = h;
            lo[j] = (_Float16)(vv[j] - (float)h);
        }
        _Float16* dst = Alds + (size_t)f * 1024 + (size_t)l * 8;
        *(f16x8*)dst         = hi;
        *(f16x8*)(dst + 512) = lo;
    }
    __syncthreads();

    // ---- barrier-free K-loop ----
    f32x4 acc[4][5];
    const f32x4 vzero = {0.f, 0.f, 0.f, 0.f};
#pragma unroll
    for (int a = 0; a < 4; ++a)
#pragma unroll
        for (int b = 0; b < 5; ++b) acc[a][b] = vzero;

    const _Float16* Wb = Wf + (size_t)(g * 20 + hc * 5) * 16384 + (size_t)l * 8;

    for (int t = 0; t < 16; ++t) {
        f16x8 Bh[5], Bl[5];
#pragma unroll
        for (int cf = 0; cf < 5; ++cf) {
            const _Float16* wp = Wb + (size_t)cf * 16384 + (size_t)t * 1024;
            Bh[cf] = *(const f16x8*)wp;
            Bl[cf] = *(const f16x8*)(wp + 512);
        }
        f16x8 Ah[4], Al[4];
#pragma unroll
        for (int rf = 0; rf < 4; ++rf) {
            const _Float16* ap = Alds + (size_t)(rf * 16 + t) * 1024 + (size_t)l * 8;
            Ah[rf] = *(const f16x8*)ap;
            Al[rf] = *(const f16x8*)(ap + 512);
        }
#pragma unroll
        for (int cf = 0; cf < 5; ++cf)
#pragma unroll
            for (int rf = 0; rf < 4; ++rf) {
                acc[rf][cf] = __builtin_amdgcn_mfma_f32_16x16x32_f16(Ah[rf], Bh[cf], acc[rf][cf], 0, 0, 0);
                acc[rf][cf] = __builtin_amdgcn_mfma_f32_16x16x32_f16(Ah[rf], Bl[cf], acc[rf][cf], 0, 0, 0);
                acc[rf][cf] = __builtin_amdgcn_mfma_f32_16x16x32_f16(Al[rf], Bh[cf], acc[rf][cf], 0, 0, 0);
            }
    }

    __syncthreads();   // all A reads complete -> smem reusable

    // epilogue scratch carved from smem
    float* red_m = (float*)smem;            // [2][64][4]
    float* red_s = red_m + 512;
    float* red_z = red_s + 512;
    int*   red_i = (int*)(red_z + 512);
    float* mfin  = (float*)(red_i + 512);   // [2][64]
    float* wrowS = mfin + 128;
    int*   idxf  = (int*)(wrowS + 128);

    // ---- bias ----
#pragma unroll
    for (int cf = 0; cf < 5; ++cf) {
        float bb = bias[g * KK + hc * 80 + 16 * cf + ln];
#pragma unroll
        for (int rf = 0; rf < 4; ++rf) {
            acc[rf][cf][0] += bb; acc[rf][cf][1] += bb;
            acc[rf][cf][2] += bb; acc[rf][cf][3] += bb;
        }
    }

    // ---- per-row stats over this wave's 80 cols (16-lane shfl reduce) ----
#pragma unroll
    for (int rf = 0; rf < 4; ++rf) {
#pragma unroll
        for (int reg = 0; reg < 4; ++reg) {
            const int row = 16 * rf + 4 * q + reg;
            const float* gp = gumbel + ((size_t)(n0 + row) * GG + g) * KK + hc * 80 + ln;
            float lm = -3.0e38f, zm = -3.0e38f;
            int zi = 0;
#pragma unroll
            for (int cf = 0; cf < 5; ++cf) {
                float v = acc[rf][cf][reg];
                lm = fmaxf(lm, v);
                float z = v + gp[16 * cf];
                if (z > zm) { zm = z; zi = hc * 80 + 16 * cf + ln; }  // first-index tie rule
            }
#pragma unroll
            for (int d = 1; d <= 8; d <<= 1) {
                lm = fmaxf(lm, __shfl_xor(lm, d));
                float zo = __shfl_xor(zm, d);
                int   io = __shfl_xor(zi, d);
                if (zo > zm || (zo == zm && io < zi)) { zm = zo; zi = io; }
            }
            float s = 0.f;
#pragma unroll
            for (int cf = 0; cf < 5; ++cf) s += __expf(acc[rf][cf][reg] - lm);
#pragma unroll
            for (int d = 1; d <= 8; d <<= 1) s += __shfl_xor(s, d);
            if (ln == 0) {
                const int base = (g * 64 + row) * 4 + hc;
                red_m[base] = lm; red_s[base] = s;
                red_z[base] = zm; red_i[base] = zi;
            }
        }
    }
    __syncthreads();

    // ---- combine 4 col-halves per (group,row) ----
    if (tid < 128) {
        const int gg = tid >> 6, r = tid & 63;
        const int b0 = (gg * 64 + r) * 4;
        float m = red_m[b0];
        m = fmaxf(m, red_m[b0 + 1]); m = fmaxf(m, red_m[b0 + 2]); m = fmaxf(m, red_m[b0 + 3]);
        float Z = 0.f;
        float zb = -3.0e38f; int ib = 0;
#pragma unroll
        for (int h = 0; h < 4; ++h) {
            Z += red_s[b0 + h] * __expf(red_m[b0 + h] - m);
            if (red_z[b0 + h] > zb) { zb = red_z[b0 + h]; ib = red_i[b0 + h]; }  // ascending h: first max wins
        }
        idxf[gg * 64 + r]  = ib;
        mfin[gg * 64 + r]  = m;
        wrowS[gg * 64 + r] = ((mask[n0 + r] != 0) ? 1.0f : 0.0f) / Z;
    }
    __syncthreads();

    // ---- marginal: per-col partials over this block's 64 rows ----
    float cs[5] = {0.f, 0.f, 0.f, 0.f, 0.f};
#pragma unroll
    for (int rf = 0; rf < 4; ++rf) {
#pragma unroll
        for (int reg = 0; reg < 4; ++reg) {
            const int row = 16 * rf + 4 * q + reg;
            const float mf = mfin[g * 64 + row], wv = wrowS[g * 64 + row];
#pragma unroll
            for (int cf = 0; cf < 5; ++cf)
                cs[cf] += __expf(acc[rf][cf][reg] - mf) * wv;
        }
    }
#pragma unroll
    for (int cf = 0; cf < 5; ++cf) {
        float v = cs[cf];
        v += __shfl_xor(v, 16);
        v += __shfl_xor(v, 32);
        if (l < 16) atomicAdd(&marg[g * KK + hc * 80 + 16 * cf + l], v);
    }

    // ---- codevector gather ----
    for (int e = tid; e < 64 * 256; e += 512) {
        const int row = e >> 8, c = e & 255, gg = c >> 7, d = c & 127;
        out[(size_t)(n0 + row) * 256 + c] =
            cv[((size_t)gg * KK + idxf[gg * 64 + row]) * DPG + d];
    }
}

// ---------- perplexity finalize ----------
__global__ __launch_bounds__(256) void finalize_kernel(
    const int* __restrict__ mask, const float* __restrict__ marg,
    float* __restrict__ perp_out)
{
    __shared__ float red[256];
    __shared__ float hg[GG];
    const int tid = threadIdx.x;

    int cnt = 0;
    for (int n = tid; n < NN; n += 256) cnt += (mask[n] != 0) ? 1 : 0;
    red[tid] = (float)cnt;
    __syncthreads();
    for (int s = 128; s > 0; s >>= 1) {
        if (tid < s) red[tid] += red[tid + s];
        __syncthreads();
    }
    const float invc = 1.0f / red[0];
    __syncthreads();

    for (int g = 0; g < GG; ++g) {
        float h = 0.0f;
        for (int c = tid; c < KK; c += 256) {
            float m = marg[g * KK + c] * invc;
            h += m * logf(m + EPSL);
        }
        red[tid] = h;
        __syncthreads();
        for (int s = 128; s > 0; s >>= 1) {
            if (tid < s) red[tid] += red[tid + s];
            __syncthreads();
        }
        if (tid == 0) hg[g] = red[0];
        __syncthreads();
    }
    if (tid == 0) perp_out[0] = expf(-hg[0]) + expf(-hg[1]);
}

extern "C" void kernel_launch(void* const* d_in, const int* in_sizes, int n_in,
                              void* d_out, int out_size, void* d_ws, size_t ws_size,
                              hipStream_t stream)
{
    const float* H      = (const float*)d_in[0];   // (32,2048,512) f32
    const int*   mask   = (const int*)d_in[1];     // (32,2048) bool->int32
    const float* gumbel = (const float*)d_in[2];   // (131072,320) f32
    const float* W      = (const float*)d_in[3];   // (640,512) f32
    const float* bias   = (const float*)d_in[4];   // (640,) f32
    const float* cv     = (const float*)d_in[5];   // (1,640,128) f32

    float*     out  = (float*)d_out;               // 16777216 + 1 floats
    float*     marg = (float*)d_ws;                // 640 f32 accumulator
    _Float16*  Wf   = (_Float16*)((char*)d_ws + 4096);  // 1.31 MB f16 frags

    hipMemsetAsync(marg, 0, GG * KK * sizeof(float), stream);
    prep_w<<<160, 256, 0, stream>>>(W, Wf);
    vq_main<<<1024, 512, 0, stream>>>(H, mask, gumbel, Wf, bias, cv, out, marg);
    finalize_kernel<<<1, 256, 0, stream>>>(mask, marg, out + (size_t)NN * GG * DPG);
}